// Round 5
// baseline (608.044 us; speedup 1.0000x reference)
//
#include <hip/hip_runtime.h>

#define SEQ 720
#define DIM 2048
#define NH 16
#define HD 128
#define CACHE 11520
#define KSP 8
#define LOG2E 1.4426950408889634f
#define SM_SCALE 0.08838834764831845f  // 1/sqrt(128)
#define CSCL (SM_SCALE * LOG2E)

typedef unsigned short u16;
typedef unsigned int u32;
typedef __bf16 bf8_t __attribute__((ext_vector_type(8)));
typedef float f4 __attribute__((ext_vector_type(4)));

__device__ __forceinline__ float bf2f(u16 v) {
    union { u32 u; float f; } t; t.u = ((u32)v) << 16; return t.f;
}
__device__ __forceinline__ u16 f2bf(float f) {
    union { float f; u32 u; } t; t.f = f;
    u32 u = t.u;
    return (u16)((u + 0x7fffu + ((u >> 16) & 1u)) >> 16);
}
// native conversion — 1 VALU op vs 5
__device__ __forceinline__ u16 f2bf_fast(float f) {
    __bf16 h = (__bf16)f;
    return __builtin_bit_cast(u16, h);
}
__device__ __forceinline__ bf8_t ld_bf8(const u16* p) {
    const u16* pa = (const u16*)__builtin_assume_aligned(p, 16);
    bf8_t r;
    __builtin_memcpy(&r, pa, 16);
    return r;
}
__device__ __forceinline__ void st8(u16* p, const u16* v) {
    __builtin_memcpy((u16*)__builtin_assume_aligned(p, 16), v, 16);
}
// dtype-dispatched 8-element load (+cvt to bf16). f32 branch is wave-uniform.
__device__ __forceinline__ void ld8_cvt(const void* base, size_t off, int f32, u16* dst) {
    if (f32) {
        const float* p = (const float*)base + off;
        float v[8];
        __builtin_memcpy(v, (const float*)__builtin_assume_aligned(p, 16), 32);
        #pragma unroll
        for (int i = 0; i < 8; i++) dst[i] = f2bf(v[i]);
    } else {
        const u16* p = (const u16*)base + off;
        __builtin_memcpy(dst, (const u16*)__builtin_assume_aligned(p, 16), 16);
    }
}
__device__ __forceinline__ float ld1(const void* base, size_t off, int f32) {
    return f32 ? ((const float*)base)[off] : bf2f(((const u16*)base)[off]);
}
__device__ __forceinline__ int ls_from(const int* cs_p, const int* sink_p) {
    const int cs = cs_p[0], sink = sink_p[0];
    const int rolling = CACHE - sink;
    int ls = (cs - sink) % rolling + sink;
    if (ls > CACHE - SEQ) ls = CACHE - SEQ;
    return ls;
}

// async global->LDS, 16B per lane. LDS dest is wave-uniform base + lane*16.
__device__ __forceinline__ void cp16_lds(u16* lds, const u16* g) {
    __builtin_amdgcn_global_load_lds(
        (const __attribute__((address_space(1))) void*)g,
        (__attribute__((address_space(3))) void*)lds,
        16, 0, 0);
}

// ---------------------------------------------------------------------------
// Dtype probe (fp32 vs bf16 inputs) — proven.
// ---------------------------------------------------------------------------
__global__ __launch_bounds__(256) void detect_kernel(const void* probe, int* flag) {
    __shared__ int cnt[256];
    const int tid = threadIdx.x;
    const u16* p = (const u16*)probe;
    int bad = 0;
    for (int i = tid; i < 4096; i += 256) {
        int e = (p[i] >> 7) & 0xFF;
        bad += (e < 0x60 || e > 0x90) ? 1 : 0;
    }
    cnt[tid] = bad;
    __syncthreads();
    if (tid == 0) {
        int s = 0;
        for (int i = 0; i < 256; i++) s += cnt[i];
        flag[0] = (s > 256) ? 1 : 0;
    }
}

// ---------------------------------------------------------------------------
// GEMM2 (round-5: CONVERSION-FUSED): C[M x 2048] = A * W^T + bias.
// A/W/bias read in their native dtype (fp32 or bf16) and converted during
// register staging — the cvt3 pre-pass kernels are deleted entirely.
// M-tile 64 (round-4 win), 4 waves = 2(M) x 2(N), each 32x64.
// ---------------------------------------------------------------------------
__device__ __forceinline__ void gemm2_body(const void* __restrict__ A, int aF32,
                                           const void* __restrict__ W,
                                           const void* __restrict__ bias, int wF32,
                                           void* __restrict__ C, int cF32, int M)
{
    __shared__ __align__(16) u16 As[64 * 64];
    __shared__ __align__(16) u16 Bs[128 * 64];
    const int tid = threadIdx.x;
    const int wv = tid >> 6, lane = tid & 63, quad = lane >> 4, l16 = lane & 15;
    const int n0 = blockIdx.x * 128, m0 = blockIdx.y * 64;
    const int wr = (wv & 1) * 32, wc = (wv >> 1) * 64;

    f4 acc[2][4];
    #pragma unroll
    for (int i = 0; i < 2; i++)
        #pragma unroll
        for (int j = 0; j < 4; j++)
            acc[i][j] = f4{0.f, 0.f, 0.f, 0.f};

    const int srow = tid >> 3, scb = tid & 7;   // 32 rows x 8 chunks per pass

    for (int kb = 0; kb < DIM / 64; kb++) {
        const int k0 = kb * 64;
        u16 avt[2][8], bvt[4][8];
        #pragma unroll
        for (int i = 0; i < 2; i++) {
            const int row = srow + 32 * i;
            int gm = m0 + row; if (gm >= M) gm = M - 1;   // clamp: pad rows recompute
            ld8_cvt(A, (size_t)gm * DIM + k0 + scb * 8, aF32, avt[i]);
        }
        #pragma unroll
        for (int i = 0; i < 4; i++) {
            const int row = srow + 32 * i;
            ld8_cvt(W, (size_t)(n0 + row) * DIM + k0 + scb * 8, wF32, bvt[i]);
        }
        __syncthreads();
        #pragma unroll
        for (int i = 0; i < 2; i++) {
            const int row = srow + 32 * i;
            st8(&As[row * 64 + ((scb ^ (row & 7)) * 8)], avt[i]);
        }
        #pragma unroll
        for (int i = 0; i < 4; i++) {
            const int row = srow + 32 * i;
            st8(&Bs[row * 64 + ((scb ^ (row & 7)) * 8)], bvt[i]);
        }
        __syncthreads();
        #pragma unroll
        for (int s = 0; s < 2; s++) {
            bf8_t af[2], bfr[4];
            #pragma unroll
            for (int i = 0; i < 2; i++) {
                const int m = wr + i * 16 + l16;
                af[i]  = ld_bf8(&As[m * 64 + (((s * 4 + quad) ^ (m & 7)) * 8)]);
            }
            #pragma unroll
            for (int i = 0; i < 4; i++) {
                const int n = wc + i * 16 + l16;
                bfr[i] = ld_bf8(&Bs[n * 64 + (((s * 4 + quad) ^ (n & 7)) * 8)]);
            }
            #pragma unroll
            for (int mi = 0; mi < 2; mi++)
                #pragma unroll
                for (int nj = 0; nj < 4; nj++)
                    acc[mi][nj] = __builtin_amdgcn_mfma_f32_16x16x32_bf16(af[mi], bfr[nj], acc[mi][nj], 0, 0, 0);
        }
    }

    #pragma unroll
    for (int mi = 0; mi < 2; mi++) {
        const int rowb = m0 + wr + mi * 16 + quad * 4;
        #pragma unroll
        for (int r = 0; r < 4; r++) {
            if (rowb + r < M) {
                #pragma unroll
                for (int nj = 0; nj < 4; nj++) {
                    const int col = n0 + wc + nj * 16 + l16;
                    float v = acc[mi][nj][r] + ld1(bias, col, wF32);
                    if (cF32) ((float*)C)[(size_t)(rowb + r) * DIM + col] = v;
                    else      ((u16*)C)[(size_t)(rowb + r) * DIM + col] = f2bf(v);
                }
            }
        }
    }
}

__global__ __launch_bounds__(256) void gemm2_qkv_kernel(
    const void* __restrict__ X,
    const void* __restrict__ w0, const void* __restrict__ w1, const void* __restrict__ w2,
    const void* __restrict__ b0, const void* __restrict__ b1, const void* __restrict__ b2,
    u16* __restrict__ o0, u16* __restrict__ o1, u16* __restrict__ o2,
    const int* __restrict__ dflag, int M)
{
    const int z = blockIdx.z;
    const void* W = (z == 0) ? w0 : (z == 1) ? w1 : w2;
    const void* B = (z == 0) ? b0 : (z == 1) ? b1 : b2;
    u16* O = (z == 0) ? o0 : (z == 1) ? o1 : o2;
    const int f32 = dflag[0];
    gemm2_body(X, f32, W, B, f32, O, 0, M);
}

__global__ __launch_bounds__(256) void gemm2_o_kernel(
    const u16* __restrict__ X, const void* __restrict__ W,
    const void* __restrict__ B, void* __restrict__ O,
    const int* __restrict__ dflag, int M)
{
    const int f32 = dflag[0];
    gemm2_body(X, 0, W, B, f32, O, f32, M);   // out dtype follows input dtype
}

// ---------------------------------------------------------------------------
// RMSNorm + RoPE, in place (proven)
// ---------------------------------------------------------------------------
__global__ __launch_bounds__(256) void normrope_kernel(
    u16* __restrict__ qbuf, u16* __restrict__ kbuf,
    const void* __restrict__ nqw, const void* __restrict__ nkw,
    const void* __restrict__ fcos, const void* __restrict__ fsin,
    const int* __restrict__ dflag)
{
    const int f32 = dflag[0];
    const int row = blockIdx.x, z = blockIdx.y;
    const int tid = threadIdx.x, lane = tid & 63, wvi = tid >> 6;
    u16* buf = ((z == 0) ? qbuf : kbuf) + (size_t)row * DIM + tid * 8;
    u16 in[8];
    __builtin_memcpy(in, (const u16*)__builtin_assume_aligned(buf, 16), 16);
    float x[8];
    #pragma unroll
    for (int i = 0; i < 8; i++) x[i] = bf2f(in[i]);
    float ss = 0.f;
    #pragma unroll
    for (int i = 0; i < 8; i++) ss += x[i] * x[i];
    ss += __shfl_xor(ss, 32); ss += __shfl_xor(ss, 16); ss += __shfl_xor(ss, 8);
    ss += __shfl_xor(ss, 4);  ss += __shfl_xor(ss, 2);  ss += __shfl_xor(ss, 1);
    __shared__ float red[4];
    if (lane == 0) red[wvi] = ss;
    __syncthreads();
    const float rinv = rsqrtf((red[0] + red[1] + red[2] + red[3]) * (1.0f / DIM) + 1e-6f);
    const void* wn = (z == 0) ? nqw : nkw;
    float y[8];
    #pragma unroll
    for (int i = 0; i < 8; i++) y[i] = x[i] * rinv * ld1(wn, tid * 8 + i, f32);
    const int dd = (tid * 8) & (HD - 1);
    const int cb = row * 64 + (dd >> 1);
    u16 outv[8];
    #pragma unroll
    for (int p = 0; p < 4; p++) {
        float cv = ld1(fcos, cb + p, f32), sv = ld1(fsin, cb + p, f32);
        float xr = y[2 * p], xi = y[2 * p + 1];
        outv[2 * p]     = f2bf(xr * cv - xi * sv);
        outv[2 * p + 1] = f2bf(xr * sv + xi * cv);
    }
    __builtin_memcpy((u16*)__builtin_assume_aligned(buf, 16), outv, 16);
}

// ---------------------------------------------------------------------------
// KV pre-pass (proven): Kb[h][key][d] bf16; Vt[h][d][key] bf16 transposed.
// ---------------------------------------------------------------------------
__global__ __launch_bounds__(256) void cvtk_kernel(
    const void* __restrict__ cache_k, const u16* __restrict__ kr,
    u16* __restrict__ Kb, const int* __restrict__ cs_p,
    const int* __restrict__ sink_p, const int* __restrict__ dflag)
{
    const int f32 = dflag[0];
    const int kt = blockIdx.x, h = blockIdx.y, tid = threadIdx.x;
    const int ls = ls_from(cs_p, sink_p);
    #pragma unroll
    for (int i = 0; i < 8; i++) {
        const int idx = i * 2048 + tid * 8;
        const int key = kt * 128 + (idx >> 7);
        const int d0 = idx & 127;
        u16 tmp[8];
        if (key >= ls && key < ls + SEQ)
            ld8_cvt(kr, (size_t)(key - ls) * DIM + h * HD + d0, 0, tmp);
        else
            ld8_cvt(cache_k, (size_t)key * DIM + h * HD + d0, f32, tmp);
        st8(&Kb[((size_t)h * CACHE + key) * HD + d0], tmp);
    }
}

__device__ __forceinline__ int swz(int ky, int cb) {
    return (cb ^ (ky >> 3) ^ ((ky & 7) << 1)) & 15;
}

__global__ __launch_bounds__(256) void cvtv_kernel(
    const void* __restrict__ cache_v, const u16* __restrict__ vr,
    u16* __restrict__ Vt, const int* __restrict__ cs_p,
    const int* __restrict__ sink_p, const int* __restrict__ dflag)
{
    __shared__ __align__(16) u16 Vtile[128 * 128];
    const int f32 = dflag[0];
    const int kt = blockIdx.x, h = blockIdx.y, tid = threadIdx.x;
    const int ls = ls_from(cs_p, sink_p);
    #pragma unroll
    for (int i = 0; i < 8; i++) {
        const int idx = i * 2048 + tid * 8;
        const int ky = idx >> 7;
        const int d0 = idx & 127;
        const int key = kt * 128 + ky;
        u16 tmp[8];
        if (key >= ls && key < ls + SEQ)
            ld8_cvt(vr, (size_t)(key - ls) * DIM + h * HD + d0, 0, tmp);
        else
            ld8_cvt(cache_v, (size_t)key * DIM + h * HD + d0, f32, tmp);
        st8(&Vtile[ky * 128 + swz(ky, d0 >> 3) * 8], tmp);
    }
    __syncthreads();
    #pragma unroll
    for (int i = 0; i < 8; i++) {
        const int oidx = i * 2048 + tid * 8;
        const int d = oidx >> 7;
        const int k8 = oidx & 127;
        u16 o[8];
        #pragma unroll
        for (int j = 0; j < 8; j++) {
            const int ky = k8 + j;
            o[j] = Vtile[ky * 128 + swz(ky, d >> 3) * 8 + (d & 7)];
        }
        st8(&Vt[((size_t)h * HD + d) * CACHE + kt * 128 + k8], o);
    }
}

// ---------------------------------------------------------------------------
// Flash attention: LDS-staged 2-phase pipeline + one-tile skewed PV (control:
// unchanged from round 4 except pL atomics -> plain per-kc partial stores).
// ---------------------------------------------------------------------------
__global__ __launch_bounds__(256, 3) void attn2_kernel(
    const u16* __restrict__ qr, const u16* __restrict__ Kb, const u16* __restrict__ Vt,
    float* __restrict__ pO, float* __restrict__ pLp)
{
    __shared__ __align__(16) u16 Klds[2][32 * 128];
    __shared__ __align__(16) u16 Vlds[3][128 * 32];
    __shared__ __align__(16) u16 Ps[4][32 * 40];
    const int tid = threadIdx.x;
    const int wvi = tid >> 6, lane = tid & 63, quad = lane >> 4, l16 = lane & 15;
    const int kc = blockIdx.x, qb = blockIdx.y, h = blockIdx.z;
    const int q0 = qb * 128 + wvi * 32;
    const int kch = CACHE / KSP;          // 1440
    const int ktiles = kch / 32;          // 45

    bf8_t aQ[2][4];
    #pragma unroll
    for (int mi = 0; mi < 2; mi++) {
        int qrow = q0 + mi * 16 + l16; if (qrow >= SEQ) qrow = SEQ - 1;
        const u16* qp = qr + (size_t)qrow * DIM + h * HD + quad * 8;
        #pragma unroll
        for (int dc = 0; dc < 4; dc++) aQ[mi][dc] = ld_bf8(qp + dc * 32);
    }

    f4 O[2][8];
    float lsum[2][4];
    #pragma unroll
    for (int mi = 0; mi < 2; mi++) {
        #pragma unroll
        for (int dc = 0; dc < 8; dc++) O[mi][dc] = f4{0.f, 0.f, 0.f, 0.f};
        #pragma unroll
        for (int r = 0; r < 4; r++) lsum[mi][r] = 0.f;
    }

    const u16* kbase = Kb + ((size_t)h * CACHE + (size_t)kc * kch) * HD;
    const u16* vbase = Vt + (size_t)h * HD * CACHE + (size_t)kc * kch;

    const int s0 = tid, s1 = tid + 256;
    const int koff0 = (s0 >> 4) * HD + (((s0 & 15) ^ ((s0 >> 4) & 15)) * 8);
    const int koff1 = (s1 >> 4) * HD + (((s1 & 15) ^ ((s1 >> 4) & 15)) * 8);
    const size_t voff0 = (size_t)(s0 >> 2) * CACHE
                       + (((s0 & 3) ^ ((s0 >> 2) & 3) ^ ((s0 >> 4) & 3)) * 8);
    const size_t voff1 = (size_t)(s1 >> 2) * CACHE
                       + (((s1 & 3) ^ ((s1 >> 2) & 3) ^ ((s1 >> 4) & 3)) * 8);

    auto stageK = [&](int t, int b) {
        const u16* kp = kbase + (size_t)t * 32 * HD;
        cp16_lds(&Klds[b][wvi * 512], kp + koff0);
        cp16_lds(&Klds[b][2048 + wvi * 512], kp + koff1);
    };
    auto stageV = [&](int t, int b) {
        const u16* vp = vbase + t * 32;
        cp16_lds(&Vlds[b][wvi * 512], vp + voff0);
        cp16_lds(&Vlds[b][2048 + wvi * 512], vp + voff1);
    };
    auto qkt = [&](int b, f4 sc[2][2]) {
        bf8_t kf[8];
        #pragma unroll
        for (int dc = 0; dc < 4; dc++) {
            const int g8 = ((quad + 4 * dc) ^ l16) * 8;
            kf[dc]     = ld_bf8(&Klds[b][l16 * HD + g8]);
            kf[4 + dc] = ld_bf8(&Klds[b][(16 + l16) * HD + g8]);
        }
        #pragma unroll
        for (int mi = 0; mi < 2; mi++) { sc[mi][0] = f4{0.f,0.f,0.f,0.f}; sc[mi][1] = f4{0.f,0.f,0.f,0.f}; }
        #pragma unroll
        for (int dc = 0; dc < 4; dc++) {
            #pragma unroll
            for (int mi = 0; mi < 2; mi++) {
                sc[mi][0] = __builtin_amdgcn_mfma_f32_16x16x32_bf16(aQ[mi][dc], kf[dc],     sc[mi][0], 0, 0, 0);
                sc[mi][1] = __builtin_amdgcn_mfma_f32_16x16x32_bf16(aQ[mi][dc], kf[4 + dc], sc[mi][1], 0, 0, 0);
            }
        }
    };
    auto smax = [&](const f4 sc[2][2]) {
        #pragma unroll
        for (int mi = 0; mi < 2; mi++) {
            #pragma unroll
            for (int r = 0; r < 4; r++) {
                float p0 = exp2f(sc[mi][0][r] * CSCL);
                float p1 = exp2f(sc[mi][1][r] * CSCL);
                lsum[mi][r] += p0 + p1;
                const int prow = mi * 16 + quad * 4 + r;
                Ps[wvi][prow * 40 + l16]      = f2bf_fast(p0);
                Ps[wvi][prow * 40 + 16 + l16] = f2bf_fast(p1);
            }
        }
    };
    const int vq8 = (quad ^ (l16 & 3) ^ (l16 >> 2)) * 8;   // V read granule*8
    auto pv = [&](bf8_t ap0, bf8_t ap1, int vb) {
        bf8_t vf[8];
        #pragma unroll
        for (int dc = 0; dc < 8; dc++)
            vf[dc] = ld_bf8(&Vlds[vb][(dc * 16 + l16) * 32 + vq8]);
        #pragma unroll
        for (int dc = 0; dc < 8; dc++) {
            O[0][dc] = __builtin_amdgcn_mfma_f32_16x16x32_bf16(ap0, vf[dc], O[0][dc], 0, 0, 0);
            O[1][dc] = __builtin_amdgcn_mfma_f32_16x16x32_bf16(ap1, vf[dc], O[1][dc], 0, 0, 0);
        }
    };

    // ---- prologue: stage tile 0 into K[0]/V[0] ----
    stageK(0, 0);
    stageV(0, 0);
    __syncthreads();

    // ---- peeled iteration 0: QK(0), smax(0); stage(1) ----
    {
        stageK(1, 1);
        stageV(1, 1);
        f4 sc[2][2];
        qkt(0, sc);
        smax(sc);
        __syncthreads();
    }

    // ---- main loop t = 1..ktiles-1: stage(t+1), QK(t), PV(t-1), smax(t) ----
    int vr = 0, vs = 2;                    // (t-1)%3, (t+1)%3 at t=1
    for (int t = 1; t < ktiles; t++) {
        const int kb = t & 1;
        if (t + 1 < ktiles) {
            stageK(t + 1, kb ^ 1);
            stageV(t + 1, vs);
        }
        f4 sc[2][2];
        qkt(kb, sc);
        // apf read MUST precede smax's overwrite of Ps (same-wave, in-order)
        bf8_t ap0 = ld_bf8(&Ps[wvi][l16 * 40 + quad * 8]);
        bf8_t ap1 = ld_bf8(&Ps[wvi][(16 + l16) * 40 + quad * 8]);
        smax(sc);
        pv(ap0, ap1, vr);
        __syncthreads();
        vr = (vr == 2) ? 0 : vr + 1;
        vs = (vs == 2) ? 0 : vs + 1;
    }

    // ---- epilogue: PV(ktiles-1) ----
    {
        bf8_t ap0 = ld_bf8(&Ps[wvi][l16 * 40 + quad * 8]);
        bf8_t ap1 = ld_bf8(&Ps[wvi][(16 + l16) * 40 + quad * 8]);
        pv(ap0, ap1, vr);
    }

    #pragma unroll
    for (int mi = 0; mi < 2; mi++)
        #pragma unroll
        for (int r = 0; r < 4; r++) {
            float s = lsum[mi][r];
            s += __shfl_xor(s, 1); s += __shfl_xor(s, 2);
            s += __shfl_xor(s, 4); s += __shfl_xor(s, 8);
            lsum[mi][r] = s;
        }
    #pragma unroll
    for (int mi = 0; mi < 2; mi++) {
        #pragma unroll
        for (int r = 0; r < 4; r++) {
            const int q = q0 + mi * 16 + quad * 4 + r;
            if (q < SEQ) {
                const size_t rb = (size_t)(h * SEQ + q);
                const size_t pb = (rb * KSP + kc) * HD;
                #pragma unroll
                for (int dc = 0; dc < 8; dc++)
                    pO[pb + dc * 16 + l16] = O[mi][dc][r];
                if (l16 == 0) pLp[rb * KSP + kc] = lsum[mi][r];  // plain store
            }
        }
    }
}

__global__ __launch_bounds__(128) void combine2_kernel(
    const float* __restrict__ pO, const float* __restrict__ pLp,
    u16* __restrict__ attn)
{
    const int q = blockIdx.x, h = blockIdx.y, d = threadIdx.x;
    const size_t rb = (size_t)(h * SEQ + q);
    float num = 0.f, den = 0.f;
    #pragma unroll
    for (int s = 0; s < KSP; s++) {
        num += pO[(rb * KSP + s) * HD + d];
        den += pLp[rb * KSP + s];
    }
    attn[(size_t)q * DIM + h * HD + d] = f2bf(num / den);
}

// ---------------------------------------------------------------------------
extern "C" void kernel_launch(void* const* d_in, const int* in_sizes, int n_in,
                              void* d_out, int out_size, void* d_ws, size_t ws_size,
                              hipStream_t stream)
{
    const void* x    = d_in[0];
    const void* q_w  = d_in[1];
    const void* q_b  = d_in[2];
    const void* k_w  = d_in[3];
    const void* k_b  = d_in[4];
    const void* v_w  = d_in[5];
    const void* v_b  = d_in[6];
    const void* o_w  = d_in[7];
    const void* o_b  = d_in[8];
    const void* nqw  = d_in[9];
    const void* nkw  = d_in[10];
    const void* cK   = d_in[11];
    const void* cV   = d_in[12];
    const void* fcos = d_in[13];
    const void* fsin = d_in[14];
    const int* cs_p   = (const int*)d_in[15];
    const int* sink_p = (const int*)d_in[17];

    char* ws = (char*)d_ws;
    const size_t SZB  = (size_t)SEQ * DIM * 2;        //  2,949,120
    const size_t KBsz = (size_t)NH * CACHE * HD * 2;  // 47,185,920
    const size_t PO1  = (size_t)NH * SEQ * HD * 4;    //  5,898,240

    int*  dflag = (int*)ws;
    u16*  q_l   = (u16*)(ws + 256);
    u16*  k_l   = (u16*)(ws + 256 + SZB);
    u16*  v_l   = (u16*)(ws + 256 + 2 * SZB);
    u16*  attn  = (u16*)(ws + 256 + 3 * SZB);
    char* pbase = ws + 256 + 4 * SZB;
    u16*   Kb = (u16*)pbase;
    u16*   Vt = (u16*)(pbase + KBsz);
    float* pO = (float*)(pbase + 2 * KBsz);
    // pL partials live in v_l's region (free after cvtv consumes v_l):
    // KSP * NH * SEQ * 4 = 368,640 B << SZB.
    float* pLp = (float*)v_l;

    dim3 blk(256);
    detect_kernel<<<1, blk, 0, stream>>>(q_w, dflag);

    // phase 1: QKV projection (conversion-fused) + norm/rope
    gemm2_qkv_kernel<<<dim3(16, 12, 3), blk, 0, stream>>>(
        x, q_w, k_w, v_w, q_b, k_b, v_b, q_l, k_l, v_l, dflag, SEQ);
    normrope_kernel<<<dim3(SEQ, 2), blk, 0, stream>>>(
        q_l, k_l, nqw, nkw, fcos, fsin, dflag);

    // phase 2: KV merge/convert/transpose + attention + combine
    cvtk_kernel<<<dim3(CACHE / 128, NH), blk, 0, stream>>>(cK, k_l, Kb, cs_p, sink_p, dflag);
    cvtv_kernel<<<dim3(CACHE / 128, NH), blk, 0, stream>>>(cV, v_l, Vt, cs_p, sink_p, dflag);
    attn2_kernel<<<dim3(KSP, 6, NH), blk, 0, stream>>>(q_l, Kb, Vt, pO, pLp);
    combine2_kernel<<<dim3(SEQ, NH), dim3(128), 0, stream>>>(pO, pLp, attn);

    // phase 3: output projection (conversion-fused, reads o_w/o_b natively)
    gemm2_o_kernel<<<dim3(16, 12, 1), blk, 0, stream>>>(
        attn, o_w, o_b, d_out, dflag, SEQ);
}

// Round 6
// 493.938 us; speedup vs baseline: 1.2310x; 1.2310x over previous
//
#include <hip/hip_runtime.h>

#define SEQ 720
#define DIM 2048
#define NH 16
#define HD 128
#define CACHE 11520
#define KSP 8
#define LOG2E 1.4426950408889634f
#define SM_SCALE 0.08838834764831845f  // 1/sqrt(128)
#define CSCL (SM_SCALE * LOG2E)

typedef unsigned short u16;
typedef unsigned int u32;
typedef __bf16 bf8_t __attribute__((ext_vector_type(8)));
typedef float f4 __attribute__((ext_vector_type(4)));

__device__ __forceinline__ float bf2f(u16 v) {
    union { u32 u; float f; } t; t.u = ((u32)v) << 16; return t.f;
}
__device__ __forceinline__ u16 f2bf(float f) {
    union { float f; u32 u; } t; t.f = f;
    u32 u = t.u;
    return (u16)((u + 0x7fffu + ((u >> 16) & 1u)) >> 16);
}
// native RNE conversion — 1 VALU op
__device__ __forceinline__ u16 f2bf_fast(float f) {
    __bf16 h = (__bf16)f;
    return __builtin_bit_cast(u16, h);
}
__device__ __forceinline__ bf8_t ld_bf8(const u16* p) {
    const u16* pa = (const u16*)__builtin_assume_aligned(p, 16);
    bf8_t r;
    __builtin_memcpy(&r, pa, 16);
    return r;
}
__device__ __forceinline__ void st8(u16* p, const u16* v) {
    __builtin_memcpy((u16*)__builtin_assume_aligned(p, 16), v, 16);
}
__device__ __forceinline__ void ld8_cvt(const void* base, size_t off, int f32, u16* dst) {
    if (f32) {
        const float* p = (const float*)base + off;
        float v[8];
        __builtin_memcpy(v, (const float*)__builtin_assume_aligned(p, 16), 32);
        #pragma unroll
        for (int i = 0; i < 8; i++) dst[i] = f2bf(v[i]);
    } else {
        const u16* p = (const u16*)base + off;
        __builtin_memcpy(dst, (const u16*)__builtin_assume_aligned(p, 16), 16);
    }
}
__device__ __forceinline__ float ld1(const void* base, size_t off, int f32) {
    return f32 ? ((const float*)base)[off] : bf2f(((const u16*)base)[off]);
}
__device__ __forceinline__ int ls_from(const int* cs_p, const int* sink_p) {
    const int cs = cs_p[0], sink = sink_p[0];
    const int rolling = CACHE - sink;
    int ls = (cs - sink) % rolling + sink;
    if (ls > CACHE - SEQ) ls = CACHE - SEQ;
    return ls;
}

// async global->LDS, 16B per lane. LDS dest is wave-uniform base + lane*16.
__device__ __forceinline__ void cp16_lds(u16* lds, const u16* g) {
    __builtin_amdgcn_global_load_lds(
        (const __attribute__((address_space(1))) void*)g,
        (__attribute__((address_space(3))) void*)lds,
        16, 0, 0);
}

// ---------------------------------------------------------------------------
// Dtype probe (fp32 vs bf16 inputs) — proven.
// ---------------------------------------------------------------------------
__global__ __launch_bounds__(256) void detect_kernel(const void* probe, int* flag) {
    __shared__ int cnt[256];
    const int tid = threadIdx.x;
    const u16* p = (const u16*)probe;
    int bad = 0;
    for (int i = tid; i < 4096; i += 256) {
        int e = (p[i] >> 7) & 0xFF;
        bad += (e < 0x60 || e > 0x90) ? 1 : 0;
    }
    cnt[tid] = bad;
    __syncthreads();
    if (tid == 0) {
        int s = 0;
        for (int i = 0; i < 256; i++) s += cnt[i];
        flag[0] = (s > 256) ? 1 : 0;
    }
}

// ---------------------------------------------------------------------------
// cvt3: fp32(or bf16 copy) -> bf16, 3 source/dest pairs via grid.y. (restored:
// round-5 proved conversion-fused GEMM staging is a 2.5x regression — the
// fp32 register round-trip + 240 cvt-ops/thread/K-step serializes at 2
// blocks/CU. Pre-converted bf16 weights + async LDS staging instead.)
// ---------------------------------------------------------------------------
__global__ __launch_bounds__(256) void cvt3_kernel(
    const void* __restrict__ s0, const void* __restrict__ s1, const void* __restrict__ s2,
    u16* __restrict__ d0, u16* __restrict__ d1, u16* __restrict__ d2,
    int n, const int* __restrict__ dflag)
{
    const int f32 = dflag[0];
    const int z = blockIdx.y;
    const void* s = (z == 0) ? s0 : (z == 1) ? s1 : s2;
    u16* d = (z == 0) ? d0 : (z == 1) ? d1 : d2;
    const int idx = (blockIdx.x * 256 + threadIdx.x) * 8;
    if (idx < n) {
        u16 t[8];
        ld8_cvt(s, idx, f32, t);
        st8(d + idx, t);
    }
}

// ---------------------------------------------------------------------------
// GEMM2 (round-6): bf16 A/W + global_load_lds double-buffered 2-phase staging
// (the attn2 round-2 recipe: stage(t+1) in flight across compute(t), one
// barrier per K-step drains it). Swizzle both-sides: linear LDS dest +
// inverse-swizzled global source (g ^ (row&7)) + swizzled frag reads.
// Bias read natively (ld1) in the epilogue. M-tile 64, 4 waves 2Mx2N.
// LDS 2*(8+16)KB = 48KB.
// ---------------------------------------------------------------------------
__device__ __forceinline__ void gemm2_body(const u16* __restrict__ A,
                                           const u16* __restrict__ W,
                                           const void* __restrict__ bias, int bF32,
                                           void* __restrict__ C, int cF32, int M)
{
    __shared__ __align__(16) u16 As[2][64 * 64];
    __shared__ __align__(16) u16 Bs[2][128 * 64];
    const int tid = threadIdx.x;
    const int wv = tid >> 6, lane = tid & 63, quad = lane >> 4, l16 = lane & 15;
    const int n0 = blockIdx.x * 128, m0 = blockIdx.y * 64;
    const int wr = (wv & 1) * 32, wc = (wv >> 1) * 64;

    f4 acc[2][4];
    #pragma unroll
    for (int i = 0; i < 2; i++)
        #pragma unroll
        for (int j = 0; j < 4; j++)
            acc[i][j] = f4{0.f, 0.f, 0.f, 0.f};

    // Per-thread staging source offsets (element units, k0 added per step).
    // As: 512 slots (16B), wave w issue i covers slots w*128+i*64+lane.
    //   slot s -> row=s>>3, g=s&7; source col-granule = g ^ (row&7).
    // Bs: 1024 slots, wave w issue i covers slots w*256+i*64+lane.
    size_t aoff[2];
    #pragma unroll
    for (int i = 0; i < 2; i++) {
        const int s = wv * 128 + i * 64 + lane;
        const int row = s >> 3, g = s & 7;
        int gm = m0 + row; if (gm >= M) gm = M - 1;   // clamp: pad rows recompute
        aoff[i] = (size_t)gm * DIM + ((g ^ (row & 7)) * 8);
    }
    size_t boff[4];
    #pragma unroll
    for (int i = 0; i < 4; i++) {
        const int s = wv * 256 + i * 64 + lane;
        const int row = s >> 3, g = s & 7;
        boff[i] = (size_t)(n0 + row) * DIM + ((g ^ (row & 7)) * 8);
    }

    auto stage = [&](int kb, int b) {
        const int k0 = kb * 64;
        #pragma unroll
        for (int i = 0; i < 2; i++)
            cp16_lds(&As[b][wv * 1024 + i * 512], A + aoff[i] + k0);
        #pragma unroll
        for (int i = 0; i < 4; i++)
            cp16_lds(&Bs[b][wv * 2048 + i * 512], W + boff[i] + k0);
    };

    stage(0, 0);
    __syncthreads();

    for (int kb = 0; kb < DIM / 64; kb++) {
        const int b = kb & 1;
        if (kb + 1 < DIM / 64) stage(kb + 1, b ^ 1);
        #pragma unroll
        for (int s = 0; s < 2; s++) {
            bf8_t af[2], bfr[4];
            #pragma unroll
            for (int i = 0; i < 2; i++) {
                const int m = wr + i * 16 + l16;
                af[i]  = ld_bf8(&As[b][m * 64 + (((s * 4 + quad) ^ (m & 7)) * 8)]);
            }
            #pragma unroll
            for (int i = 0; i < 4; i++) {
                const int n = wc + i * 16 + l16;
                bfr[i] = ld_bf8(&Bs[b][n * 64 + (((s * 4 + quad) ^ (n & 7)) * 8)]);
            }
            #pragma unroll
            for (int mi = 0; mi < 2; mi++)
                #pragma unroll
                for (int nj = 0; nj < 4; nj++)
                    acc[mi][nj] = __builtin_amdgcn_mfma_f32_16x16x32_bf16(af[mi], bfr[nj], acc[mi][nj], 0, 0, 0);
        }
        __syncthreads();   // drains stage(kb+1); protects buffer reuse
    }

    #pragma unroll
    for (int mi = 0; mi < 2; mi++) {
        const int rowb = m0 + wr + mi * 16 + quad * 4;
        #pragma unroll
        for (int r = 0; r < 4; r++) {
            if (rowb + r < M) {
                #pragma unroll
                for (int nj = 0; nj < 4; nj++) {
                    const int col = n0 + wc + nj * 16 + l16;
                    float v = acc[mi][nj][r] + ld1(bias, col, bF32);
                    if (cF32) ((float*)C)[(size_t)(rowb + r) * DIM + col] = v;
                    else      ((u16*)C)[(size_t)(rowb + r) * DIM + col] = f2bf_fast(v);
                }
            }
        }
    }
}

__global__ __launch_bounds__(256) void gemm2_qkv_kernel(
    const u16* __restrict__ X,
    const u16* __restrict__ w0, const u16* __restrict__ w1, const u16* __restrict__ w2,
    const void* __restrict__ b0, const void* __restrict__ b1, const void* __restrict__ b2,
    u16* __restrict__ o0, u16* __restrict__ o1, u16* __restrict__ o2,
    const int* __restrict__ dflag, int M)
{
    const int z = blockIdx.z;
    const u16* W = (z == 0) ? w0 : (z == 1) ? w1 : w2;
    const void* B = (z == 0) ? b0 : (z == 1) ? b1 : b2;
    u16* O = (z == 0) ? o0 : (z == 1) ? o1 : o2;
    gemm2_body(X, W, B, dflag[0], O, 0, M);
}

__global__ __launch_bounds__(256) void gemm2_o_kernel(
    const u16* __restrict__ X, const u16* __restrict__ W,
    const void* __restrict__ B, void* __restrict__ O,
    const int* __restrict__ dflag, int M)
{
    const int f32 = dflag[0];
    gemm2_body(X, W, B, f32, O, f32, M);   // out dtype follows input dtype
}

// ---------------------------------------------------------------------------
// RMSNorm + RoPE, in place (proven)
// ---------------------------------------------------------------------------
__global__ __launch_bounds__(256) void normrope_kernel(
    u16* __restrict__ qbuf, u16* __restrict__ kbuf,
    const void* __restrict__ nqw, const void* __restrict__ nkw,
    const void* __restrict__ fcos, const void* __restrict__ fsin,
    const int* __restrict__ dflag)
{
    const int f32 = dflag[0];
    const int row = blockIdx.x, z = blockIdx.y;
    const int tid = threadIdx.x, lane = tid & 63, wvi = tid >> 6;
    u16* buf = ((z == 0) ? qbuf : kbuf) + (size_t)row * DIM + tid * 8;
    u16 in[8];
    __builtin_memcpy(in, (const u16*)__builtin_assume_aligned(buf, 16), 16);
    float x[8];
    #pragma unroll
    for (int i = 0; i < 8; i++) x[i] = bf2f(in[i]);
    float ss = 0.f;
    #pragma unroll
    for (int i = 0; i < 8; i++) ss += x[i] * x[i];
    ss += __shfl_xor(ss, 32); ss += __shfl_xor(ss, 16); ss += __shfl_xor(ss, 8);
    ss += __shfl_xor(ss, 4);  ss += __shfl_xor(ss, 2);  ss += __shfl_xor(ss, 1);
    __shared__ float red[4];
    if (lane == 0) red[wvi] = ss;
    __syncthreads();
    const float rinv = rsqrtf((red[0] + red[1] + red[2] + red[3]) * (1.0f / DIM) + 1e-6f);
    const void* wn = (z == 0) ? nqw : nkw;
    float y[8];
    #pragma unroll
    for (int i = 0; i < 8; i++) y[i] = x[i] * rinv * ld1(wn, tid * 8 + i, f32);
    const int dd = (tid * 8) & (HD - 1);
    const int cb = row * 64 + (dd >> 1);
    u16 outv[8];
    #pragma unroll
    for (int p = 0; p < 4; p++) {
        float cv = ld1(fcos, cb + p, f32), sv = ld1(fsin, cb + p, f32);
        float xr = y[2 * p], xi = y[2 * p + 1];
        outv[2 * p]     = f2bf(xr * cv - xi * sv);
        outv[2 * p + 1] = f2bf(xr * sv + xi * cv);
    }
    __builtin_memcpy((u16*)__builtin_assume_aligned(buf, 16), outv, 16);
}

// ---------------------------------------------------------------------------
// KV pre-pass (proven): Kb[h][key][d] bf16; Vt[h][d][key] bf16 transposed.
// ---------------------------------------------------------------------------
__global__ __launch_bounds__(256) void cvtk_kernel(
    const void* __restrict__ cache_k, const u16* __restrict__ kr,
    u16* __restrict__ Kb, const int* __restrict__ cs_p,
    const int* __restrict__ sink_p, const int* __restrict__ dflag)
{
    const int f32 = dflag[0];
    const int kt = blockIdx.x, h = blockIdx.y, tid = threadIdx.x;
    const int ls = ls_from(cs_p, sink_p);
    #pragma unroll
    for (int i = 0; i < 8; i++) {
        const int idx = i * 2048 + tid * 8;
        const int key = kt * 128 + (idx >> 7);
        const int d0 = idx & 127;
        u16 tmp[8];
        if (key >= ls && key < ls + SEQ)
            ld8_cvt(kr, (size_t)(key - ls) * DIM + h * HD + d0, 0, tmp);
        else
            ld8_cvt(cache_k, (size_t)key * DIM + h * HD + d0, f32, tmp);
        st8(&Kb[((size_t)h * CACHE + key) * HD + d0], tmp);
    }
}

__device__ __forceinline__ int swz(int ky, int cb) {
    return (cb ^ (ky >> 3) ^ ((ky & 7) << 1)) & 15;
}

__global__ __launch_bounds__(256) void cvtv_kernel(
    const void* __restrict__ cache_v, const u16* __restrict__ vr,
    u16* __restrict__ Vt, const int* __restrict__ cs_p,
    const int* __restrict__ sink_p, const int* __restrict__ dflag)
{
    __shared__ __align__(16) u16 Vtile[128 * 128];
    const int f32 = dflag[0];
    const int kt = blockIdx.x, h = blockIdx.y, tid = threadIdx.x;
    const int ls = ls_from(cs_p, sink_p);
    #pragma unroll
    for (int i = 0; i < 8; i++) {
        const int idx = i * 2048 + tid * 8;
        const int ky = idx >> 7;
        const int d0 = idx & 127;
        const int key = kt * 128 + ky;
        u16 tmp[8];
        if (key >= ls && key < ls + SEQ)
            ld8_cvt(vr, (size_t)(key - ls) * DIM + h * HD + d0, 0, tmp);
        else
            ld8_cvt(cache_v, (size_t)key * DIM + h * HD + d0, f32, tmp);
        st8(&Vtile[ky * 128 + swz(ky, d0 >> 3) * 8], tmp);
    }
    __syncthreads();
    #pragma unroll
    for (int i = 0; i < 8; i++) {
        const int oidx = i * 2048 + tid * 8;
        const int d = oidx >> 7;
        const int k8 = oidx & 127;
        u16 o[8];
        #pragma unroll
        for (int j = 0; j < 8; j++) {
            const int ky = k8 + j;
            o[j] = Vtile[ky * 128 + swz(ky, d >> 3) * 8 + (d & 7)];
        }
        st8(&Vt[((size_t)h * HD + d) * CACHE + kt * 128 + k8], o);
    }
}

// ---------------------------------------------------------------------------
// Flash attention: LDS-staged 2-phase pipeline + one-tile skewed PV
// (unchanged control; plain per-kc pL partial stores).
// ---------------------------------------------------------------------------
__global__ __launch_bounds__(256, 3) void attn2_kernel(
    const u16* __restrict__ qr, const u16* __restrict__ Kb, const u16* __restrict__ Vt,
    float* __restrict__ pO, float* __restrict__ pLp)
{
    __shared__ __align__(16) u16 Klds[2][32 * 128];
    __shared__ __align__(16) u16 Vlds[3][128 * 32];
    __shared__ __align__(16) u16 Ps[4][32 * 40];
    const int tid = threadIdx.x;
    const int wvi = tid >> 6, lane = tid & 63, quad = lane >> 4, l16 = lane & 15;
    const int kc = blockIdx.x, qb = blockIdx.y, h = blockIdx.z;
    const int q0 = qb * 128 + wvi * 32;
    const int kch = CACHE / KSP;          // 1440
    const int ktiles = kch / 32;          // 45

    bf8_t aQ[2][4];
    #pragma unroll
    for (int mi = 0; mi < 2; mi++) {
        int qrow = q0 + mi * 16 + l16; if (qrow >= SEQ) qrow = SEQ - 1;
        const u16* qp = qr + (size_t)qrow * DIM + h * HD + quad * 8;
        #pragma unroll
        for (int dc = 0; dc < 4; dc++) aQ[mi][dc] = ld_bf8(qp + dc * 32);
    }

    f4 O[2][8];
    float lsum[2][4];
    #pragma unroll
    for (int mi = 0; mi < 2; mi++) {
        #pragma unroll
        for (int dc = 0; dc < 8; dc++) O[mi][dc] = f4{0.f, 0.f, 0.f, 0.f};
        #pragma unroll
        for (int r = 0; r < 4; r++) lsum[mi][r] = 0.f;
    }

    const u16* kbase = Kb + ((size_t)h * CACHE + (size_t)kc * kch) * HD;
    const u16* vbase = Vt + (size_t)h * HD * CACHE + (size_t)kc * kch;

    const int s0 = tid, s1 = tid + 256;
    const int koff0 = (s0 >> 4) * HD + (((s0 & 15) ^ ((s0 >> 4) & 15)) * 8);
    const int koff1 = (s1 >> 4) * HD + (((s1 & 15) ^ ((s1 >> 4) & 15)) * 8);
    const size_t voff0 = (size_t)(s0 >> 2) * CACHE
                       + (((s0 & 3) ^ ((s0 >> 2) & 3) ^ ((s0 >> 4) & 3)) * 8);
    const size_t voff1 = (size_t)(s1 >> 2) * CACHE
                       + (((s1 & 3) ^ ((s1 >> 2) & 3) ^ ((s1 >> 4) & 3)) * 8);

    auto stageK = [&](int t, int b) {
        const u16* kp = kbase + (size_t)t * 32 * HD;
        cp16_lds(&Klds[b][wvi * 512], kp + koff0);
        cp16_lds(&Klds[b][2048 + wvi * 512], kp + koff1);
    };
    auto stageV = [&](int t, int b) {
        const u16* vp = vbase + t * 32;
        cp16_lds(&Vlds[b][wvi * 512], vp + voff0);
        cp16_lds(&Vlds[b][2048 + wvi * 512], vp + voff1);
    };
    auto qkt = [&](int b, f4 sc[2][2]) {
        bf8_t kf[8];
        #pragma unroll
        for (int dc = 0; dc < 4; dc++) {
            const int g8 = ((quad + 4 * dc) ^ l16) * 8;
            kf[dc]     = ld_bf8(&Klds[b][l16 * HD + g8]);
            kf[4 + dc] = ld_bf8(&Klds[b][(16 + l16) * HD + g8]);
        }
        #pragma unroll
        for (int mi = 0; mi < 2; mi++) { sc[mi][0] = f4{0.f,0.f,0.f,0.f}; sc[mi][1] = f4{0.f,0.f,0.f,0.f}; }
        #pragma unroll
        for (int dc = 0; dc < 4; dc++) {
            #pragma unroll
            for (int mi = 0; mi < 2; mi++) {
                sc[mi][0] = __builtin_amdgcn_mfma_f32_16x16x32_bf16(aQ[mi][dc], kf[dc],     sc[mi][0], 0, 0, 0);
                sc[mi][1] = __builtin_amdgcn_mfma_f32_16x16x32_bf16(aQ[mi][dc], kf[4 + dc], sc[mi][1], 0, 0, 0);
            }
        }
    };
    auto smax = [&](const f4 sc[2][2]) {
        #pragma unroll
        for (int mi = 0; mi < 2; mi++) {
            #pragma unroll
            for (int r = 0; r < 4; r++) {
                float p0 = exp2f(sc[mi][0][r] * CSCL);
                float p1 = exp2f(sc[mi][1][r] * CSCL);
                lsum[mi][r] += p0 + p1;
                const int prow = mi * 16 + quad * 4 + r;
                Ps[wvi][prow * 40 + l16]      = f2bf_fast(p0);
                Ps[wvi][prow * 40 + 16 + l16] = f2bf_fast(p1);
            }
        }
    };
    const int vq8 = (quad ^ (l16 & 3) ^ (l16 >> 2)) * 8;   // V read granule*8
    auto pv = [&](bf8_t ap0, bf8_t ap1, int vb) {
        bf8_t vf[8];
        #pragma unroll
        for (int dc = 0; dc < 8; dc++)
            vf[dc] = ld_bf8(&Vlds[vb][(dc * 16 + l16) * 32 + vq8]);
        #pragma unroll
        for (int dc = 0; dc < 8; dc++) {
            O[0][dc] = __builtin_amdgcn_mfma_f32_16x16x32_bf16(ap0, vf[dc], O[0][dc], 0, 0, 0);
            O[1][dc] = __builtin_amdgcn_mfma_f32_16x16x32_bf16(ap1, vf[dc], O[1][dc], 0, 0, 0);
        }
    };

    // ---- prologue: stage tile 0 into K[0]/V[0] ----
    stageK(0, 0);
    stageV(0, 0);
    __syncthreads();

    // ---- peeled iteration 0: QK(0), smax(0); stage(1) ----
    {
        stageK(1, 1);
        stageV(1, 1);
        f4 sc[2][2];
        qkt(0, sc);
        smax(sc);
        __syncthreads();
    }

    // ---- main loop t = 1..ktiles-1: stage(t+1), QK(t), PV(t-1), smax(t) ----
    int vr = 0, vs = 2;                    // (t-1)%3, (t+1)%3 at t=1
    for (int t = 1; t < ktiles; t++) {
        const int kb = t & 1;
        if (t + 1 < ktiles) {
            stageK(t + 1, kb ^ 1);
            stageV(t + 1, vs);
        }
        f4 sc[2][2];
        qkt(kb, sc);
        // apf read MUST precede smax's overwrite of Ps (same-wave, in-order)
        bf8_t ap0 = ld_bf8(&Ps[wvi][l16 * 40 + quad * 8]);
        bf8_t ap1 = ld_bf8(&Ps[wvi][(16 + l16) * 40 + quad * 8]);
        smax(sc);
        pv(ap0, ap1, vr);
        __syncthreads();
        vr = (vr == 2) ? 0 : vr + 1;
        vs = (vs == 2) ? 0 : vs + 1;
    }

    // ---- epilogue: PV(ktiles-1) ----
    {
        bf8_t ap0 = ld_bf8(&Ps[wvi][l16 * 40 + quad * 8]);
        bf8_t ap1 = ld_bf8(&Ps[wvi][(16 + l16) * 40 + quad * 8]);
        pv(ap0, ap1, vr);
    }

    #pragma unroll
    for (int mi = 0; mi < 2; mi++)
        #pragma unroll
        for (int r = 0; r < 4; r++) {
            float s = lsum[mi][r];
            s += __shfl_xor(s, 1); s += __shfl_xor(s, 2);
            s += __shfl_xor(s, 4); s += __shfl_xor(s, 8);
            lsum[mi][r] = s;
        }
    #pragma unroll
    for (int mi = 0; mi < 2; mi++) {
        #pragma unroll
        for (int r = 0; r < 4; r++) {
            const int q = q0 + mi * 16 + quad * 4 + r;
            if (q < SEQ) {
                const size_t rb = (size_t)(h * SEQ + q);
                const size_t pb = (rb * KSP + kc) * HD;
                #pragma unroll
                for (int dc = 0; dc < 8; dc++)
                    pO[pb + dc * 16 + l16] = O[mi][dc][r];
                if (l16 == 0) pLp[rb * KSP + kc] = lsum[mi][r];  // plain store
            }
        }
    }
}

__global__ __launch_bounds__(128) void combine2_kernel(
    const float* __restrict__ pO, const float* __restrict__ pLp,
    u16* __restrict__ attn)
{
    const int q = blockIdx.x, h = blockIdx.y, d = threadIdx.x;
    const size_t rb = (size_t)(h * SEQ + q);
    float num = 0.f, den = 0.f;
    #pragma unroll
    for (int s = 0; s < KSP; s++) {
        num += pO[(rb * KSP + s) * HD + d];
        den += pLp[rb * KSP + s];
    }
    attn[(size_t)q * DIM + h * HD + d] = f2bf(num / den);
}

// ---------------------------------------------------------------------------
extern "C" void kernel_launch(void* const* d_in, const int* in_sizes, int n_in,
                              void* d_out, int out_size, void* d_ws, size_t ws_size,
                              hipStream_t stream)
{
    const void* x    = d_in[0];
    const void* q_w  = d_in[1];
    const void* q_b  = d_in[2];
    const void* k_w  = d_in[3];
    const void* k_b  = d_in[4];
    const void* v_w  = d_in[5];
    const void* v_b  = d_in[6];
    const void* o_w  = d_in[7];
    const void* o_b  = d_in[8];
    const void* nqw  = d_in[9];
    const void* nkw  = d_in[10];
    const void* cK   = d_in[11];
    const void* cV   = d_in[12];
    const void* fcos = d_in[13];
    const void* fsin = d_in[14];
    const int* cs_p   = (const int*)d_in[15];
    const int* sink_p = (const int*)d_in[17];

    char* ws = (char*)d_ws;
    const size_t SZB  = (size_t)SEQ * DIM * 2;        //  2,949,120
    const size_t KBsz = (size_t)NH * CACHE * HD * 2;  // 47,185,920

    int*  dflag = (int*)ws;
    u16*  q_l   = (u16*)(ws + 256);
    u16*  k_l   = (u16*)(ws + 256 + SZB);
    u16*  v_l   = (u16*)(ws + 256 + 2 * SZB);
    u16*  attn  = (u16*)(ws + 256 + 3 * SZB);
    char* pbase = ws + 256 + 4 * SZB;
    u16*   Kb = (u16*)pbase;
    u16*   Vt = (u16*)(pbase + KBsz);
    float* pO = (float*)(pbase + 2 * KBsz);
    // pL partials in v_l's region (free after cvtv consumes v_l):
    // KSP * NH * SEQ * 4 = 368,640 B << SZB.
    float* pLp = (float*)v_l;

    // phase-1 aliases inside the pO region (consumed before attn2 writes pO):
    u16* Wq = (u16*)pO;
    u16* Wk = Wq + (size_t)DIM * DIM;
    u16* Wv = Wk + (size_t)DIM * DIM;
    u16* x_bf = Wv + (size_t)DIM * DIM;
    // phase-3 alias (after combine2 consumed pO):
    u16* Wo = (u16*)pO;

    dim3 blk(256);
    detect_kernel<<<1, blk, 0, stream>>>(q_w, dflag);

    // phase 1: weight/x conversion + QKV projection + norm/rope
    cvt3_kernel<<<dim3(DIM * DIM / 2048, 3), blk, 0, stream>>>(
        q_w, k_w, v_w, Wq, Wk, Wv, DIM * DIM, dflag);
    cvt3_kernel<<<dim3(SEQ * DIM / 2048, 1), blk, 0, stream>>>(
        x, x, x, x_bf, x_bf, x_bf, SEQ * DIM, dflag);
    gemm2_qkv_kernel<<<dim3(16, 12, 3), blk, 0, stream>>>(
        x_bf, Wq, Wk, Wv, q_b, k_b, v_b, q_l, k_l, v_l, dflag, SEQ);
    normrope_kernel<<<dim3(SEQ, 2), blk, 0, stream>>>(
        q_l, k_l, nqw, nkw, fcos, fsin, dflag);

    // phase 2: KV merge/convert/transpose + attention + combine
    cvtk_kernel<<<dim3(CACHE / 128, NH), blk, 0, stream>>>(cK, k_l, Kb, cs_p, sink_p, dflag);
    cvtv_kernel<<<dim3(CACHE / 128, NH), blk, 0, stream>>>(cV, v_l, Vt, cs_p, sink_p, dflag);
    attn2_kernel<<<dim3(KSP, 6, NH), blk, 0, stream>>>(q_l, Kb, Vt, pO, pLp);
    combine2_kernel<<<dim3(SEQ, NH), dim3(128), 0, stream>>>(pO, pLp, attn);

    // phase 3: output projection (o_w converted into now-free pO scratch)
    cvt3_kernel<<<dim3(DIM * DIM / 2048, 1), blk, 0, stream>>>(
        o_w, o_w, o_w, Wo, Wo, Wo, DIM * DIM, dflag);
    gemm2_o_kernel<<<dim3(16, 12, 1), blk, 0, stream>>>(
        attn, Wo, o_b, d_out, dflag, SEQ);
}